// Round 4
// baseline (347.991 us; speedup 1.0000x reference)
//
#include <hip/hip_runtime.h>
#include <hip/hip_bf16.h>

// Featurizer: protein graph features + fused linear + layernorm.
// Round-6 changes vs round-5 (346.6us; k_edge 182us, rest ~165us):
//  * FUSE k_node into k_edge dispatch (k_main): role by blockIdx%6 (5 edge :
//    1 node interleave) so node blocks fill edge blocks' ~45% idle issue slots
//    and one launch gap disappears. k_packw+k_frames fused into k_prep.
//  * edge: KS_A 32->24 (A-stage 24KB, LDS 30.8KB) -> 5 blocks/CU,
//    __launch_bounds__(256,5). Pass B = 19 ksteps RECOMPUTED in the window
//    (round-1-proven faster than reg-carry; only dirs for pairs 0..23 carried).
//  * hand-RNE bf16 (bit-identical to __float2bfloat16 for finite x, ~4 ops).
//  * edge epilogue: thread p handles channels {8j+p} -> C_s reads <=2-way
//    bank conflicts (free) instead of 4-way.

#define N_RES   30000
#define N_ATOMS 6
#define LFLAT   (N_RES * N_ATOMS)   // 180000
#define N_EDGES 300000
#define HID     128
#define NODE_IN 44
#define EDGE_IN 688
#define KSTEPS  43                   // 688 / 16
#define KS_A    24                   // ksteps in MFMA pass A (24KB stage)
#define EPSF    1e-6f
#define LN_EPS  1e-5f
#define MTILE   32                   // edges per block (MFMA M)
#define RPB     16                   // residues per node block
#define NEBLK   (N_EDGES / MTILE)    // 9375
#define NNBLK   (N_RES / RPB)        // 1875  (9375 = 5*1875 -> clean 5:1 mix)

typedef short short8 __attribute__((ext_vector_type(8)));
typedef float float16v __attribute__((ext_vector_type(16)));

// Hand RNE f32->bf16: bit-identical to __float2bfloat16 for finite inputs
// (all features are finite by construction); ~4 VALU vs ~6-7 for the builtin.
static __device__ __forceinline__ unsigned int bfbits(float x) {
    unsigned int u = __builtin_bit_cast(unsigned int, x);
    return (u + 0x7fffu + ((u >> 16) & 1u)) >> 16;
}
static __device__ __forceinline__ unsigned short f2bf(float x) {
    return (unsigned short)bfbits(x);
}
static __device__ __forceinline__ unsigned int pk2(float lo, float hi) {
    return bfbits(lo) | (bfbits(hi) << 16);
}

struct F3 { float x, y, z; };
static __device__ __forceinline__ F3 ld3(const float* p, long idx) {   // idx in vec3 units
    F3 r; r.x = p[idx*3+0]; r.y = p[idx*3+1]; r.z = p[idx*3+2]; return r;
}
static __device__ __forceinline__ F3 ldl(const float* p, int a) {      // LDS-local atom
    F3 r; r.x = p[a*3+0]; r.y = p[a*3+1]; r.z = p[a*3+2]; return r;
}
static __device__ __forceinline__ F3 subv(F3 a, F3 b) { return {a.x-b.x, a.y-b.y, a.z-b.z}; }
static __device__ __forceinline__ float dotv(F3 a, F3 b) { return a.x*b.x + a.y*b.y + a.z*b.z; }
static __device__ __forceinline__ F3 crossv(F3 a, F3 b) {
    return {a.y*b.z - a.z*b.y, a.z*b.x - a.x*b.z, a.x*b.y - a.y*b.x};
}
static __device__ __forceinline__ F3 nrmv(F3 a) {
    float inv = rsqrtf(fmaxf(dotv(a, a), 1e-24f));
    return {a.x*inv, a.y*inv, a.z*inv};
}
static __device__ __forceinline__ float sgn(float x) { return (x > 0.f) ? 1.f : ((x < 0.f) ? -1.f : 0.f); }

// ---------------- k_prep: packw (blocks 0..42) + frames (blocks 43..160) ----------------
__global__ __launch_bounds__(256) void k_prep(
    const float* __restrict__ edge_W, const float* __restrict__ central,
    const int* __restrict__ batch,
    unsigned short* __restrict__ Wp, float* __restrict__ Qbuf, int* __restrict__ qval) {
    int bid = blockIdx.x;
    int tid = threadIdx.x;
    if (bid < KSTEPS) {
        // Wpack[s][w][lane][jj]: B[k][n], n = w*32+(lane&31), k = 16s+(lane>>5)*8+jj,
        // permuted k: k<684 -> orig k+4 (rbf/direct), k>=684 -> orig k-684 (quat).
        int s = bid;
        int w = tid >> 6, lane = tid & 63;
        int ch = w * 32 + (lane & 31);
        int kh = lane >> 5;
        uint4 out;
        uint u[4];
        #pragma unroll
        for (int jp = 0; jp < 4; ++jp) {
            int k0 = 16 * s + kh * 8 + 2 * jp;
            int ko0 = (k0     < 684) ? (k0 + 4) : (k0 - 684);
            int ko1 = (k0 + 1 < 684) ? (k0 + 5) : (k0 - 683);
            u[jp] = pk2(edge_W[(long)ko0 * HID + ch], edge_W[(long)ko1 * HID + ch]);
        }
        out.x = u[0]; out.y = u[1]; out.z = u[2]; out.w = u[3];
        *(uint4*)(Wp + ((size_t)(s * 4 + w) * 64 + lane) * 8) = out;
    } else {
        int r = (bid - KSTEPS) * 256 + tid;
        if (r >= N_RES) return;
        bool bnd   = (r > 0)         && (batch[r]   != batch[r-1]);
        bool bndn  = (r < N_RES - 1) && (batch[r+1] != batch[r]);
        bool valid = (r > 0) && (r < N_RES - 1) && !bnd && !bndn;
        float Q[9] = {0,0,0,0,0,0,0,0,0};
        if (valid) {
            F3 cp = ld3(central, (long)r-1), cc = ld3(central, (long)r), cn = ld3(central, (long)r+1);
            F3 u0 = nrmv(subv(cc, cp));
            F3 u1 = nrmv(subv(cn, cc));
            F3 b  = nrmv(subv(u0, u1));
            F3 n  = nrmv(crossv(u0, u1));
            F3 c  = crossv(b, n);
            Q[0]=b.x; Q[1]=n.x; Q[2]=c.x;     // Q[i*3+j]: i=spatial, j in {b,n,c}
            Q[3]=b.y; Q[4]=n.y; Q[5]=c.y;
            Q[6]=b.z; Q[7]=n.z; Q[8]=c.z;
        }
        #pragma unroll
        for (int k = 0; k < 9; k++) Qbuf[(size_t)r*9 + k] = Q[k];
        qval[r] = valid ? 1 : 0;
    }
}

// ---------------- k_main: edge blocks (MFMA GEMM) + node blocks, interleaved ----------------
// LDS carve (edge): Ast 0..24575 | cS 24576 (64*18 f) | qtS 29184 (32*9 f) | sS/tS 30336
// LDS carve (node): Wlds 0..22527 | feat 22528 (16*44 f) | cst 25344 (324 f) |
//                   bS 26640 | lwS 27152 | lbS 27664 | red 28176
// max 30592 -> smem[30848]; 5 blocks/CU.
__global__ __launch_bounds__(256, 5) void k_main(
    const float* __restrict__ coords, const float* __restrict__ central,
    const float* __restrict__ node_W, const float* __restrict__ node_b,
    const float* __restrict__ node_lw, const float* __restrict__ node_lb,
    const int* __restrict__ batch, const int* __restrict__ eidx,
    const unsigned short* __restrict__ Wpack, const float* __restrict__ edge_b,
    const float* __restrict__ edge_lw, const float* __restrict__ edge_lb,
    const float* __restrict__ Qbuf, const int* __restrict__ qval,
    float* __restrict__ outV, float* __restrict__ outE) {
    __shared__ __align__(16) unsigned char smem[30848];
    int bid = blockIdx.x;
    int g = bid / 6, r6 = bid - 6 * g;
    int tid = threadIdx.x;

    if (r6 != 5) {
        // =================== EDGE ROLE ===================
        int eb = g * 5 + r6;                       // 0..9374
        unsigned short* Ast = (unsigned short*)smem;
        float* cS  = (float*)(smem + 24576);       // [64][18]
        float* qtS = (float*)(smem + 29184);       // [32][9]
        int*   sS  = (int*)(smem + 30336);
        int*   tS  = sS + MTILE;
        int lane = tid & 63;
        int w = tid >> 6;
        int e0 = eb * MTILE;

        if (tid < MTILE) {
            sS[tid] = eidx[e0 + tid];
            tS[tid] = eidx[N_EDGES + e0 + tid];
        }
        __syncthreads();

        #pragma unroll
        for (int it = 0; it < 5; ++it) {
            int idx = tid + it * 256;
            if (idx < 64 * 18) {
                int slot = idx / 18;
                int rem  = idx - slot * 18;
                int res  = (slot < 32) ? sS[slot] : tS[slot - 32];
                cS[idx] = coords[(size_t)res * 18 + rem];
            }
        }

        uint2 qpk;
        if (tid < MTILE) {
            int s = sS[tid];
            int t = tS[tid];
            float Qs[9], Qt[9];
            #pragma unroll
            for (int k = 0; k < 9; k++) {
                Qs[k] = Qbuf[(size_t)s*9 + k];
                Qt[k] = Qbuf[(size_t)t*9 + k];
                qtS[tid*9 + k] = Qt[k];
            }
            float R[9];   // R[i][j] = sum_k Qt[k][i] * Qs[k][j]
            #pragma unroll
            for (int i = 0; i < 3; i++)
                #pragma unroll
                for (int jj = 0; jj < 3; jj++)
                    R[i*3+jj] = Qt[0+i]*Qs[0+jj] + Qt[3+i]*Qs[3+jj] + Qt[6+i]*Qs[6+jj];
            float m0 = 0.5f * sqrtf(fabsf(1.f + R[0] - R[4] - R[8]));
            float m1 = 0.5f * sqrtf(fabsf(1.f - R[0] + R[4] - R[8]));
            float m2 = 0.5f * sqrtf(fabsf(1.f - R[0] - R[4] + R[8]));
            float xq = sgn(R[7] - R[5]) * m0;
            float yq = sgn(R[2] - R[6]) * m1;
            float zq = sgn(R[3] - R[1]) * m2;
            float wq = 0.5f * sqrtf(fmaxf(1.f + R[0] + R[4] + R[8], 0.f));
            float inv = rsqrtf(fmaxf(xq*xq + yq*yq + zq*zq + wq*wq, 1e-24f));
            float vm = (qval[s] && qval[t]) ? 1.f : 0.f;
            qpk.x = pk2(xq * inv * vm, yq * inv * vm);
            qpk.y = pk2(zq * inv * vm, wq * inv * vm);
        }
        __syncthreads();   // cS + qtS ready

        int e  = tid & 31;
        int p0 = tid >> 5;   // 0..7

        // Round-1-verified RBF math: z_j = a8 - j*1.06666672, a8 = 0.8*sqrt(d2+eps),
        // value = __expf(-z^2); shared rsqrt for D and direction.
        #define RBF_TASK(PAIR, EV, ULO, UHI, DIR)                                        \
        {                                                                                \
            int ta = (PAIR) / 6, sa = (PAIR) - ta * 6;                                   \
            const float* cs_ = cS + (EV)*18 + sa*3;                                      \
            const float* ct_ = cS + (32+(EV))*18 + ta*3;                                 \
            float dx = cs_[0]-ct_[0], dy = cs_[1]-ct_[1], dz = cs_[2]-ct_[2];            \
            float d2_ = dx*dx + dy*dy + dz*dz;                                           \
            float t_  = d2_ + EPSF;                                                      \
            float inv_ = rsqrtf(t_);                                                     \
            float a8 = t_ * inv_ * 0.8f;                                                 \
            unsigned int uu[8];                                                          \
            _Pragma("unroll")                                                            \
            for (int i_ = 0; i_ < 8; i_++) {                                             \
                float z0 = a8 - (float)(2*i_)     * 1.06666672f;                         \
                float z1 = a8 - (float)(2*i_ + 1) * 1.06666672f;                         \
                uu[i_] = pk2(__expf(-(z0*z0)), __expf(-(z1*z1)));                        \
            }                                                                            \
            ULO.x = uu[0]; ULO.y = uu[1]; ULO.z = uu[2]; ULO.w = uu[3];                  \
            UHI.x = uu[4]; UHI.y = uu[5]; UHI.z = uu[6]; UHI.w = uu[7];                  \
            float nx = dx*inv_, ny = dy*inv_, nz = dz*inv_;                              \
            _Pragma("unroll")                                                            \
            for (int i_ = 0; i_ < 3; i_++)                                               \
                DIR[i_] = qtS[(EV)*9+0+i_]*nx + qtS[(EV)*9+3+i_]*ny + qtS[(EV)*9+6+i_]*nz; \
        }

        // dir k = 576 + pair*3 + i -> kstep 36..42 (pass B local 12..18)
        #define DIR_WRITE(PAIR, EV, DIR)                                                 \
        {                                                                                \
            _Pragma("unroll")                                                            \
            for (int i_ = 0; i_ < 3; i_++) {                                             \
                int kn = 576 + (PAIR)*3 + i_;                                            \
                int s2 = kn >> 4, r2 = kn & 15;                                          \
                Ast[(((s2 - KS_A)*64) + (r2>>3)*32 + (EV))*8 + (r2&7)] = f2bf(DIR[i_]);  \
            }                                                                            \
        }

        // ---- phase A: pairs 0..23 -> ksteps 0..23; dirs carried in 9 regs
        float vdir[3][3];
        #pragma unroll
        for (int it = 0; it < 3; ++it) {
            int pair = p0 + 8 * it;
            uint4 lo, hi;
            RBF_TASK(pair, e, lo, hi, vdir[it]);
            *(uint4*)(Ast + (pair * 64 + e) * 8)      = lo;
            *(uint4*)(Ast + (pair * 64 + 32 + e) * 8) = hi;
        }
        __syncthreads();

        // ---- MFMA pass A: ksteps 0..23
        float16v acc;
        #pragma unroll
        for (int i = 0; i < 16; i++) acc[i] = 0.f;
        const short8* Ap = (const short8*)Ast;
        const short8* Bp = (const short8*)Wpack;
        for (int s = 0; s < KS_A; ++s) {
            short8 a = Ap[s * 64 + lane];
            short8 b = Bp[(s * 4 + w) * 64 + lane];
            acc = __builtin_amdgcn_mfma_f32_32x32x16_bf16(a, b, acc, 0, 0, 0);
        }
        __syncthreads();   // pass-A staging free

        // ---- window: recompute pass-B features (pairs 24..35) + carried dirs + quat
        {
            uint4 lo, hi; float dw[3];
            RBF_TASK(24 + p0, e, lo, hi, dw);          // local kstep p0
            *(uint4*)(Ast + (p0 * 64 + e) * 8)      = lo;
            *(uint4*)(Ast + (p0 * 64 + 32 + e) * 8) = hi;
            DIR_WRITE(24 + p0, e, dw);
        }
        if (p0 >= 4) {                                  // pairs 32..35 -> local 8..11
            uint4 lo, hi; float dw[3];
            RBF_TASK(28 + p0, e, lo, hi, dw);
            *(uint4*)(Ast + ((4 + p0) * 64 + e) * 8)      = lo;
            *(uint4*)(Ast + ((4 + p0) * 64 + 32 + e) * 8) = hi;
            DIR_WRITE(28 + p0, e, dw);
        }
        #pragma unroll
        for (int it = 0; it < 3; ++it)
            DIR_WRITE(p0 + 8 * it, e, vdir[it]);
        if (tid < MTILE)   // quat: global kstep 42 -> local 18, rows 32.., jj 4..7
            *(uint2*)(Ast + ((18 * 64 + 32 + tid) * 8 + 4)) = qpk;
        __syncthreads();

        // ---- MFMA pass B: ksteps 24..42
        for (int s = KS_A; s < KSTEPS; ++s) {
            short8 a = Ap[(s - KS_A) * 64 + lane];
            short8 b = Bp[(s * 4 + w) * 64 + lane];
            acc = __builtin_amdgcn_mfma_f32_32x32x16_bf16(a, b, acc, 0, 0, 0);
        }

        // ---- epilogue: acc -> C_s, then bias + LN + store (strided slices)
        __syncthreads();
        float* C_s = (float*)smem;   // [32][132] = 16896B
        int col = lane & 31;
        #pragma unroll
        for (int r = 0; r < 16; ++r) {
            int row = (r & 3) + 8 * (r >> 2) + 4 * (lane >> 5);   // verified C/D layout (m74/m101)
            C_s[row * 132 + w * 32 + col] = acc[r];
        }
        __syncthreads();

        int ee = tid >> 3;          // 0..31
        int p  = tid & 7;           // strided channel slice {8j+p}
        const float* Crow = C_s + ee * 132;
        float x[16];
        float sum = 0.f;
        #pragma unroll
        for (int j = 0; j < 16; ++j) {
            int c = 8 * j + p;
            x[j] = Crow[c] + edge_b[c];
            sum += x[j];
        }
        #pragma unroll
        for (int m = 1; m < 8; m <<= 1) sum += __shfl_xor(sum, m, 64);
        float mu = sum * (1.f / HID);
        float vs = 0.f;
        #pragma unroll
        for (int j = 0; j < 16; ++j) { float d = x[j] - mu; vs += d * d; }
        #pragma unroll
        for (int m = 1; m < 8; m <<= 1) vs += __shfl_xor(vs, m, 64);
        float is = rsqrtf(vs * (1.f / HID) + LN_EPS);
        float* op = outE + (size_t)(e0 + ee) * HID;
        #pragma unroll
        for (int j = 0; j < 16; ++j) {
            int c = 8 * j + p;
            op[c] = (x[j] - mu) * is * edge_lw[c] + edge_lb[c];
        }
        #undef RBF_TASK
        #undef DIR_WRITE
    } else {
        // =================== NODE ROLE ===================
        int nb = g;                                // 0..1874
        float* Wlds = (float*)smem;                // 44*128 f
        float* feat = (float*)(smem + 22528);      // [16][44]
        float* cst  = (float*)(smem + 25344);      // (16+2)*18 f
        float* bS   = (float*)(smem + 26640);
        float* lwS  = (float*)(smem + 27152);
        float* lbS  = (float*)(smem + 27664);
        float* red  = (float*)(smem + 28176);      // 8 f
        int r0 = nb * RPB;

        const float4* W4 = (const float4*)node_W;
        float4* Wl4 = (float4*)Wlds;
        for (int i = tid; i < NODE_IN * HID / 4; i += 256) Wl4[i] = W4[i];
        if (tid < HID) { bS[tid] = node_b[tid]; lwS[tid] = node_lw[tid]; lbS[tid] = node_lb[tid]; }
        for (int i = tid; i < (RPB + 2) * 18; i += 256) {
            long gg = (long)(r0 - 1) * 18 + i;
            cst[i] = (gg >= 0 && gg < (long)N_RES * 18) ? coords[gg] : 0.f;
        }
        __syncthreads();

        if (tid < RPB * 11) {
            int rl = tid / 11, role = tid - rl * 11;
            int r = r0 + rl;
            bool bnd  = (r > 0)         && (batch[r]   != batch[r-1]);
            bool bndn = (r < N_RES - 1) && (batch[r+1] != batch[r]);
            const float* C = cst + (rl + 1) * 18;   // atom 0 of residue r
            if (role < 6) {
                int c = role;
                long j = (long)r * N_ATOMS + c;
                float sd = 0.f, cd = 0.f;
                bool dm = (j > 0) && (j < LFLAT - 2) && !(bnd && c == 0) && !(bndn && c >= N_ATOMS - 2);
                if (dm) {
                    F3 x0 = ldl(C, c-1), x1 = ldl(C, c), x2 = ldl(C, c+1), x3 = ldl(C, c+2);
                    F3 u1 = nrmv(subv(x1, x0)), u2 = nrmv(subv(x2, x1)), u3 = nrmv(subv(x3, x2));
                    F3 c1 = nrmv(crossv(u1, u2)), c2 = nrmv(crossv(u2, u3));
                    float cc = fminf(fmaxf(dotv(c1, c2), -1.f + EPSF), 1.f - EPSF);
                    float s  = sgn(dotv(c2, u1));
                    sd = s * sqrtf(fmaxf(1.f - cc*cc, 0.f));   // sin(s*acos(cc))
                    cd = (s != 0.f) ? cc : 1.f;                // cos
                }
                feat[rl*NODE_IN + 2*c] = sd; feat[rl*NODE_IN + 2*c+1] = cd;
                float sa = 0.f, ca = 0.f;
                bool am = (j > 0) && (j < LFLAT - 1) && !(bnd && c == 0) && !(bndn && c == N_ATOMS - 1);
                if (am) {
                    F3 x0 = ldl(C, c-1), x1 = ldl(C, c), x2 = ldl(C, c+1);
                    F3 d0 = nrmv(subv(x0, x1)), d1 = nrmv(subv(x2, x1));
                    float cv = dotv(d0, d1);
                    float t = 1.f - cv*cv + EPSF;
                    sa = t * rsqrtf(t);
                    ca = cv;
                }
                feat[rl*NODE_IN + 12 + 2*c] = sa; feat[rl*NODE_IN + 12 + 2*c + 1] = ca;
            } else {
                int a = role - 6;
                int atom = (a == 0) ? 0 : (a + 1);   // keep atoms {0,2,3,4,5}
                F3 x  = ldl(C, atom);
                F3 cx = ld3(central, (long)r);
                F3 d  = subv(x, cx);
                float d2 = dotv(d, d);
                feat[rl*NODE_IN + 24 + a] = 0.5f * __logf(d2 + EPSF);
                float inv = rsqrtf(fmaxf(d2, 1e-24f));
                float nx = d.x*inv, ny = d.y*inv, nz = d.z*inv;
                const float* Q = Qbuf + (size_t)r * 9;
                #pragma unroll
                for (int i = 0; i < 3; i++)
                    feat[rl*NODE_IN + 29 + a*3 + i] = Q[0+i]*nx + Q[3+i]*ny + Q[6+i]*nz;
            }
        }
        __syncthreads();

        int ch = tid & 127;
        int sg = tid >> 7;          // residue sub-group 0/1
        int w  = tid >> 6;          // wave 0..3
        for (int it = 0; it < 8; ++it) {
            int rl = it * 2 + sg;
            float acc = bS[ch];
            #pragma unroll
            for (int i = 0; i < NODE_IN; i++)
                acc += feat[rl*NODE_IN + i] * Wlds[i * HID + ch];
            float s = acc;
            #pragma unroll
            for (int m = 1; m < 64; m <<= 1) s += __shfl_xor(s, m, 64);
            if ((tid & 63) == 0) red[w] = s;
            __syncthreads();
            float mu = (red[2*sg] + red[2*sg+1]) * (1.f / HID);
            float dv = acc - mu;
            float q = dv * dv;
            #pragma unroll
            for (int m = 1; m < 64; m <<= 1) q += __shfl_xor(q, m, 64);
            if ((tid & 63) == 0) red[4 + w] = q;
            __syncthreads();
            float var = (red[4 + 2*sg] + red[4 + 2*sg + 1]) * (1.f / HID);
            outV[(size_t)(r0 + rl) * HID + ch] = dv * rsqrtf(var + LN_EPS) * lwS[ch] + lbS[ch];
        }
    }
}

extern "C" void kernel_launch(void* const* d_in, const int* in_sizes, int n_in,
                              void* d_out, int out_size, void* d_ws, size_t ws_size,
                              hipStream_t stream) {
    (void)in_sizes; (void)n_in; (void)out_size; (void)ws_size;
    const float* coords  = (const float*)d_in[0];
    const float* central = (const float*)d_in[1];
    const float* node_W  = (const float*)d_in[2];
    const float* node_b  = (const float*)d_in[3];
    const float* node_lw = (const float*)d_in[4];
    const float* node_lb = (const float*)d_in[5];
    const float* edge_W  = (const float*)d_in[6];
    const float* edge_b  = (const float*)d_in[7];
    const float* edge_lw = (const float*)d_in[8];
    const float* edge_lb = (const float*)d_in[9];
    const int*   batch   = (const int*)d_in[10];
    const int*   eidx    = (const int*)d_in[11];

    // ws: [Wpack bf16: 88064 el = 176128 B][Qbuf: 270000 f][qval: 30000 i] ~= 1.38 MB
    unsigned short* Wpack = (unsigned short*)d_ws;
    float* Qbuf = (float*)((char*)d_ws + (size_t)EDGE_IN * HID * 2);
    int*   qval = (int*)(Qbuf + (size_t)N_RES * 9);

    float* outV = (float*)d_out;
    float* outE = outV + (size_t)N_RES * HID;

    hipLaunchKernelGGL(k_prep, dim3(KSTEPS + (N_RES + 255) / 256), dim3(256), 0, stream,
                       edge_W, central, batch, Wpack, Qbuf, qval);
    hipLaunchKernelGGL(k_main, dim3(NEBLK + NNBLK), dim3(256), 0, stream,
                       coords, central, node_W, node_b, node_lw, node_lb, batch, eidx,
                       Wpack, edge_b, edge_lw, edge_lb, Qbuf, qval, outV, outE);
}

// Round 5
// 341.661 us; speedup vs baseline: 1.0185x; 1.0185x over previous
//
#include <hip/hip_runtime.h>
#include <hip/hip_bf16.h>

// Featurizer: protein graph features + fused linear + layernorm.
// Round-7 changes vs round-6 (348.0us; k_main 208us, WRITE 268MB, FETCH 102MB):
//  * REVERT the strided epilogue (c=8j+p, 32B-chunk stores): it caused partial
//    L2-line eviction -> write-allocate amplification (+100MB WRITE, +55MB
//    FETCH ~= +25us). Back to contiguous p*16+j slices (full 64B per thread,
//    proven 150MB WRITE in round-3). 4-way LDS conflict on C_s reads is the
//    cheaper side of that trade (1.58x on a handful of ds_reads).
//  * RE-LAND incremental exp2 chain for RBF (2 adds + v_exp per value).
//    Round-4 passed with hand-RNE pk2, convicting round-2's inline-asm
//    v_cvt_pk_bf16_f32 (not the chain) as that failure. Chain exponent error
//    <= ~2e-4 relative, far below bf16 ulp.

#define N_RES   30000
#define N_ATOMS 6
#define LFLAT   (N_RES * N_ATOMS)   // 180000
#define N_EDGES 300000
#define HID     128
#define NODE_IN 44
#define EDGE_IN 688
#define KSTEPS  43                   // 688 / 16
#define KS_A    24                   // ksteps in MFMA pass A (24KB stage)
#define EPSF    1e-6f
#define LN_EPS  1e-5f
#define MTILE   32                   // edges per block (MFMA M)
#define RPB     16                   // residues per node block
#define NEBLK   (N_EDGES / MTILE)    // 9375
#define NNBLK   (N_RES / RPB)        // 1875  (9375 = 5*1875 -> clean 5:1 mix)

typedef short short8 __attribute__((ext_vector_type(8)));
typedef float float16v __attribute__((ext_vector_type(16)));

// Hand RNE f32->bf16: bit-identical to __float2bfloat16 for finite inputs
// (all features are finite by construction); ~4 VALU vs ~6-7 for the builtin.
static __device__ __forceinline__ unsigned int bfbits(float x) {
    unsigned int u = __builtin_bit_cast(unsigned int, x);
    return (u + 0x7fffu + ((u >> 16) & 1u)) >> 16;
}
static __device__ __forceinline__ unsigned short f2bf(float x) {
    return (unsigned short)bfbits(x);
}
static __device__ __forceinline__ unsigned int pk2(float lo, float hi) {
    return bfbits(lo) | (bfbits(hi) << 16);
}
static __device__ __forceinline__ float exp2f_hw(float x) {
#if __has_builtin(__builtin_amdgcn_exp2f)
    return __builtin_amdgcn_exp2f(x);
#else
    return __expf(x * 0.69314718f);
#endif
}

struct F3 { float x, y, z; };
static __device__ __forceinline__ F3 ld3(const float* p, long idx) {   // idx in vec3 units
    F3 r; r.x = p[idx*3+0]; r.y = p[idx*3+1]; r.z = p[idx*3+2]; return r;
}
static __device__ __forceinline__ F3 ldl(const float* p, int a) {      // LDS-local atom
    F3 r; r.x = p[a*3+0]; r.y = p[a*3+1]; r.z = p[a*3+2]; return r;
}
static __device__ __forceinline__ F3 subv(F3 a, F3 b) { return {a.x-b.x, a.y-b.y, a.z-b.z}; }
static __device__ __forceinline__ float dotv(F3 a, F3 b) { return a.x*b.x + a.y*b.y + a.z*b.z; }
static __device__ __forceinline__ F3 crossv(F3 a, F3 b) {
    return {a.y*b.z - a.z*b.y, a.z*b.x - a.x*b.z, a.x*b.y - a.y*b.x};
}
static __device__ __forceinline__ F3 nrmv(F3 a) {
    float inv = rsqrtf(fmaxf(dotv(a, a), 1e-24f));
    return {a.x*inv, a.y*inv, a.z*inv};
}
static __device__ __forceinline__ float sgn(float x) { return (x > 0.f) ? 1.f : ((x < 0.f) ? -1.f : 0.f); }

// ---------------- k_prep: packw (blocks 0..42) + frames (blocks 43..160) ----------------
__global__ __launch_bounds__(256) void k_prep(
    const float* __restrict__ edge_W, const float* __restrict__ central,
    const int* __restrict__ batch,
    unsigned short* __restrict__ Wp, float* __restrict__ Qbuf, int* __restrict__ qval) {
    int bid = blockIdx.x;
    int tid = threadIdx.x;
    if (bid < KSTEPS) {
        // Wpack[s][w][lane][jj]: B[k][n], n = w*32+(lane&31), k = 16s+(lane>>5)*8+jj,
        // permuted k: k<684 -> orig k+4 (rbf/direct), k>=684 -> orig k-684 (quat).
        int s = bid;
        int w = tid >> 6, lane = tid & 63;
        int ch = w * 32 + (lane & 31);
        int kh = lane >> 5;
        uint4 out;
        uint u[4];
        #pragma unroll
        for (int jp = 0; jp < 4; ++jp) {
            int k0 = 16 * s + kh * 8 + 2 * jp;
            int ko0 = (k0     < 684) ? (k0 + 4) : (k0 - 684);
            int ko1 = (k0 + 1 < 684) ? (k0 + 5) : (k0 - 683);
            u[jp] = pk2(edge_W[(long)ko0 * HID + ch], edge_W[(long)ko1 * HID + ch]);
        }
        out.x = u[0]; out.y = u[1]; out.z = u[2]; out.w = u[3];
        *(uint4*)(Wp + ((size_t)(s * 4 + w) * 64 + lane) * 8) = out;
    } else {
        int r = (bid - KSTEPS) * 256 + tid;
        if (r >= N_RES) return;
        bool bnd   = (r > 0)         && (batch[r]   != batch[r-1]);
        bool bndn  = (r < N_RES - 1) && (batch[r+1] != batch[r]);
        bool valid = (r > 0) && (r < N_RES - 1) && !bnd && !bndn;
        float Q[9] = {0,0,0,0,0,0,0,0,0};
        if (valid) {
            F3 cp = ld3(central, (long)r-1), cc = ld3(central, (long)r), cn = ld3(central, (long)r+1);
            F3 u0 = nrmv(subv(cc, cp));
            F3 u1 = nrmv(subv(cn, cc));
            F3 b  = nrmv(subv(u0, u1));
            F3 n  = nrmv(crossv(u0, u1));
            F3 c  = crossv(b, n);
            Q[0]=b.x; Q[1]=n.x; Q[2]=c.x;     // Q[i*3+j]: i=spatial, j in {b,n,c}
            Q[3]=b.y; Q[4]=n.y; Q[5]=c.y;
            Q[6]=b.z; Q[7]=n.z; Q[8]=c.z;
        }
        #pragma unroll
        for (int k = 0; k < 9; k++) Qbuf[(size_t)r*9 + k] = Q[k];
        qval[r] = valid ? 1 : 0;
    }
}

// ---------------- k_main: edge blocks (MFMA GEMM) + node blocks, interleaved ----------------
// LDS carve (edge): Ast 0..24575 | cS 24576 (64*18 f) | qtS 29184 (32*9 f) | sS/tS 30336
// LDS carve (node): Wlds 0..22527 | feat 22528 (16*44 f) | cst 25344 (324 f) |
//                   bS 26640 | lwS 27152 | lbS 27664 | red 28176
// max 30592 -> smem[30848]; 5 blocks/CU.
__global__ __launch_bounds__(256, 5) void k_main(
    const float* __restrict__ coords, const float* __restrict__ central,
    const float* __restrict__ node_W, const float* __restrict__ node_b,
    const float* __restrict__ node_lw, const float* __restrict__ node_lb,
    const int* __restrict__ batch, const int* __restrict__ eidx,
    const unsigned short* __restrict__ Wpack, const float* __restrict__ edge_b,
    const float* __restrict__ edge_lw, const float* __restrict__ edge_lb,
    const float* __restrict__ Qbuf, const int* __restrict__ qval,
    float* __restrict__ outV, float* __restrict__ outE) {
    __shared__ __align__(16) unsigned char smem[30848];
    int bid = blockIdx.x;
    int g = bid / 6, r6 = bid - 6 * g;
    int tid = threadIdx.x;

    if (r6 != 5) {
        // =================== EDGE ROLE ===================
        int eb = g * 5 + r6;                       // 0..9374
        unsigned short* Ast = (unsigned short*)smem;
        float* cS  = (float*)(smem + 24576);       // [64][18]
        float* qtS = (float*)(smem + 29184);       // [32][9]
        int*   sS  = (int*)(smem + 30336);
        int*   tS  = sS + MTILE;
        int lane = tid & 63;
        int w = tid >> 6;
        int e0 = eb * MTILE;

        if (tid < MTILE) {
            sS[tid] = eidx[e0 + tid];
            tS[tid] = eidx[N_EDGES + e0 + tid];
        }
        __syncthreads();

        #pragma unroll
        for (int it = 0; it < 5; ++it) {
            int idx = tid + it * 256;
            if (idx < 64 * 18) {
                int slot = idx / 18;
                int rem  = idx - slot * 18;
                int res  = (slot < 32) ? sS[slot] : tS[slot - 32];
                cS[idx] = coords[(size_t)res * 18 + rem];
            }
        }

        uint2 qpk;
        if (tid < MTILE) {
            int s = sS[tid];
            int t = tS[tid];
            float Qs[9], Qt[9];
            #pragma unroll
            for (int k = 0; k < 9; k++) {
                Qs[k] = Qbuf[(size_t)s*9 + k];
                Qt[k] = Qbuf[(size_t)t*9 + k];
                qtS[tid*9 + k] = Qt[k];
            }
            float R[9];   // R[i][j] = sum_k Qt[k][i] * Qs[k][j]
            #pragma unroll
            for (int i = 0; i < 3; i++)
                #pragma unroll
                for (int jj = 0; jj < 3; jj++)
                    R[i*3+jj] = Qt[0+i]*Qs[0+jj] + Qt[3+i]*Qs[3+jj] + Qt[6+i]*Qs[6+jj];
            float m0 = 0.5f * sqrtf(fabsf(1.f + R[0] - R[4] - R[8]));
            float m1 = 0.5f * sqrtf(fabsf(1.f - R[0] + R[4] - R[8]));
            float m2 = 0.5f * sqrtf(fabsf(1.f - R[0] - R[4] + R[8]));
            float xq = sgn(R[7] - R[5]) * m0;
            float yq = sgn(R[2] - R[6]) * m1;
            float zq = sgn(R[3] - R[1]) * m2;
            float wq = 0.5f * sqrtf(fmaxf(1.f + R[0] + R[4] + R[8], 0.f));
            float inv = rsqrtf(fmaxf(xq*xq + yq*yq + zq*zq + wq*wq, 1e-24f));
            float vm = (qval[s] && qval[t]) ? 1.f : 0.f;
            qpk.x = pk2(xq * inv * vm, yq * inv * vm);
            qpk.y = pk2(zq * inv * vm, wq * inv * vm);
        }
        __syncthreads();   // cS + qtS ready

        int e  = tid & 31;
        int p0 = tid >> 5;   // 0..7

        // RBF via incremental exp2 chain: q_i = -log2e*(a8 - i*c)^2, c = 1.0666667
        //   q0 = -1.44269504*a8^2; dq0 = 3.0777494*a8 - 1.6414661; ddq = -3.2829322
        // (2 adds + 1 v_exp per value; exponent drift <= ~2e-4 abs, << bf16 ulp)
        #define RBF_TASK(PAIR, EV, ULO, UHI, DIR)                                        \
        {                                                                                \
            int ta = (PAIR) / 6, sa = (PAIR) - ta * 6;                                   \
            const float* cs_ = cS + (EV)*18 + sa*3;                                      \
            const float* ct_ = cS + (32+(EV))*18 + ta*3;                                 \
            float dx = cs_[0]-ct_[0], dy = cs_[1]-ct_[1], dz = cs_[2]-ct_[2];            \
            float d2_ = dx*dx + dy*dy + dz*dz;                                           \
            float t_  = d2_ + EPSF;                                                      \
            float inv_ = rsqrtf(t_);                                                     \
            float a8 = t_ * inv_ * 0.8f;                                                 \
            float q_  = -1.44269504f * a8 * a8;                                          \
            float dq_ = 3.0777494f * a8 - 1.6414661f;                                    \
            unsigned int uu[8];                                                          \
            _Pragma("unroll")                                                            \
            for (int i_ = 0; i_ < 8; i_++) {                                             \
                float v0_ = exp2f_hw(q_); q_ += dq_; dq_ -= 3.2829322f;                  \
                float v1_ = exp2f_hw(q_); q_ += dq_; dq_ -= 3.2829322f;                  \
                uu[i_] = pk2(v0_, v1_);                                                  \
            }                                                                            \
            ULO.x = uu[0]; ULO.y = uu[1]; ULO.z = uu[2]; ULO.w = uu[3];                  \
            UHI.x = uu[4]; UHI.y = uu[5]; UHI.z = uu[6]; UHI.w = uu[7];                  \
            float nx = dx*inv_, ny = dy*inv_, nz = dz*inv_;                              \
            _Pragma("unroll")                                                            \
            for (int i_ = 0; i_ < 3; i_++)                                               \
                DIR[i_] = qtS[(EV)*9+0+i_]*nx + qtS[(EV)*9+3+i_]*ny + qtS[(EV)*9+6+i_]*nz; \
        }

        // dir k = 576 + pair*3 + i -> kstep 36..42 (pass B local 12..18)
        #define DIR_WRITE(PAIR, EV, DIR)                                                 \
        {                                                                                \
            _Pragma("unroll")                                                            \
            for (int i_ = 0; i_ < 3; i_++) {                                             \
                int kn = 576 + (PAIR)*3 + i_;                                            \
                int s2 = kn >> 4, r2 = kn & 15;                                          \
                Ast[(((s2 - KS_A)*64) + (r2>>3)*32 + (EV))*8 + (r2&7)] = f2bf(DIR[i_]);  \
            }                                                                            \
        }

        // ---- phase A: pairs 0..23 -> ksteps 0..23; dirs carried in 9 regs
        float vdir[3][3];
        #pragma unroll
        for (int it = 0; it < 3; ++it) {
            int pair = p0 + 8 * it;
            uint4 lo, hi;
            RBF_TASK(pair, e, lo, hi, vdir[it]);
            *(uint4*)(Ast + (pair * 64 + e) * 8)      = lo;
            *(uint4*)(Ast + (pair * 64 + 32 + e) * 8) = hi;
        }
        __syncthreads();

        // ---- MFMA pass A: ksteps 0..23
        float16v acc;
        #pragma unroll
        for (int i = 0; i < 16; i++) acc[i] = 0.f;
        const short8* Ap = (const short8*)Ast;
        const short8* Bp = (const short8*)Wpack;
        for (int s = 0; s < KS_A; ++s) {
            short8 a = Ap[s * 64 + lane];
            short8 b = Bp[(s * 4 + w) * 64 + lane];
            acc = __builtin_amdgcn_mfma_f32_32x32x16_bf16(a, b, acc, 0, 0, 0);
        }
        __syncthreads();   // pass-A staging free

        // ---- window: recompute pass-B features (pairs 24..35) + carried dirs + quat
        {
            uint4 lo, hi; float dw[3];
            RBF_TASK(24 + p0, e, lo, hi, dw);          // local kstep p0
            *(uint4*)(Ast + (p0 * 64 + e) * 8)      = lo;
            *(uint4*)(Ast + (p0 * 64 + 32 + e) * 8) = hi;
            DIR_WRITE(24 + p0, e, dw);
        }
        if (p0 >= 4) {                                  // pairs 32..35 -> local 8..11
            uint4 lo, hi; float dw[3];
            RBF_TASK(28 + p0, e, lo, hi, dw);
            *(uint4*)(Ast + ((4 + p0) * 64 + e) * 8)      = lo;
            *(uint4*)(Ast + ((4 + p0) * 64 + 32 + e) * 8) = hi;
            DIR_WRITE(28 + p0, e, dw);
        }
        #pragma unroll
        for (int it = 0; it < 3; ++it)
            DIR_WRITE(p0 + 8 * it, e, vdir[it]);
        if (tid < MTILE)   // quat: global kstep 42 -> local 18, rows 32.., jj 4..7
            *(uint2*)(Ast + ((18 * 64 + 32 + tid) * 8 + 4)) = qpk;
        __syncthreads();

        // ---- MFMA pass B: ksteps 24..42
        for (int s = KS_A; s < KSTEPS; ++s) {
            short8 a = Ap[(s - KS_A) * 64 + lane];
            short8 b = Bp[(s * 4 + w) * 64 + lane];
            acc = __builtin_amdgcn_mfma_f32_32x32x16_bf16(a, b, acc, 0, 0, 0);
        }

        // ---- epilogue: acc -> C_s, then bias + LN + store (CONTIGUOUS 16-ch slices:
        //      full 64B per thread -> no partial-line write-allocate at HBM)
        __syncthreads();
        float* C_s = (float*)smem;   // [32][132] = 16896B
        int col = lane & 31;
        #pragma unroll
        for (int r = 0; r < 16; ++r) {
            int row = (r & 3) + 8 * (r >> 2) + 4 * (lane >> 5);   // verified C/D layout (m74/m101)
            C_s[row * 132 + w * 32 + col] = acc[r];
        }
        __syncthreads();

        int ee = tid >> 3;          // 0..31
        int p  = tid & 7;           // 16-channel contiguous slice
        const float* Crow = C_s + ee * 132 + p * 16;
        float x[16];
        float sum = 0.f;
        #pragma unroll
        for (int j = 0; j < 16; ++j) {
            x[j] = Crow[j] + edge_b[p * 16 + j];
            sum += x[j];
        }
        #pragma unroll
        for (int m = 1; m < 8; m <<= 1) sum += __shfl_xor(sum, m, 64);
        float mu = sum * (1.f / HID);
        float vs = 0.f;
        #pragma unroll
        for (int j = 0; j < 16; ++j) { float d = x[j] - mu; vs += d * d; }
        #pragma unroll
        for (int m = 1; m < 8; m <<= 1) vs += __shfl_xor(vs, m, 64);
        float is = rsqrtf(vs * (1.f / HID) + LN_EPS);
        float* op = outE + (size_t)(e0 + ee) * HID + p * 16;
        #pragma unroll
        for (int j = 0; j < 16; ++j) {
            int c = p * 16 + j;
            op[j] = (x[j] - mu) * is * edge_lw[c] + edge_lb[c];
        }
        #undef RBF_TASK
        #undef DIR_WRITE
    } else {
        // =================== NODE ROLE ===================
        int nb = g;                                // 0..1874
        float* Wlds = (float*)smem;                // 44*128 f
        float* feat = (float*)(smem + 22528);      // [16][44]
        float* cst  = (float*)(smem + 25344);      // (16+2)*18 f
        float* bS   = (float*)(smem + 26640);
        float* lwS  = (float*)(smem + 27152);
        float* lbS  = (float*)(smem + 27664);
        float* red  = (float*)(smem + 28176);      // 8 f
        int r0 = nb * RPB;

        const float4* W4 = (const float4*)node_W;
        float4* Wl4 = (float4*)Wlds;
        for (int i = tid; i < NODE_IN * HID / 4; i += 256) Wl4[i] = W4[i];
        if (tid < HID) { bS[tid] = node_b[tid]; lwS[tid] = node_lw[tid]; lbS[tid] = node_lb[tid]; }
        for (int i = tid; i < (RPB + 2) * 18; i += 256) {
            long gg = (long)(r0 - 1) * 18 + i;
            cst[i] = (gg >= 0 && gg < (long)N_RES * 18) ? coords[gg] : 0.f;
        }
        __syncthreads();

        if (tid < RPB * 11) {
            int rl = tid / 11, role = tid - rl * 11;
            int r = r0 + rl;
            bool bnd  = (r > 0)         && (batch[r]   != batch[r-1]);
            bool bndn = (r < N_RES - 1) && (batch[r+1] != batch[r]);
            const float* C = cst + (rl + 1) * 18;   // atom 0 of residue r
            if (role < 6) {
                int c = role;
                long j = (long)r * N_ATOMS + c;
                float sd = 0.f, cd = 0.f;
                bool dm = (j > 0) && (j < LFLAT - 2) && !(bnd && c == 0) && !(bndn && c >= N_ATOMS - 2);
                if (dm) {
                    F3 x0 = ldl(C, c-1), x1 = ldl(C, c), x2 = ldl(C, c+1), x3 = ldl(C, c+2);
                    F3 u1 = nrmv(subv(x1, x0)), u2 = nrmv(subv(x2, x1)), u3 = nrmv(subv(x3, x2));
                    F3 c1 = nrmv(crossv(u1, u2)), c2 = nrmv(crossv(u2, u3));
                    float cc = fminf(fmaxf(dotv(c1, c2), -1.f + EPSF), 1.f - EPSF);
                    float s  = sgn(dotv(c2, u1));
                    sd = s * sqrtf(fmaxf(1.f - cc*cc, 0.f));   // sin(s*acos(cc))
                    cd = (s != 0.f) ? cc : 1.f;                // cos
                }
                feat[rl*NODE_IN + 2*c] = sd; feat[rl*NODE_IN + 2*c+1] = cd;
                float sa = 0.f, ca = 0.f;
                bool am = (j > 0) && (j < LFLAT - 1) && !(bnd && c == 0) && !(bndn && c == N_ATOMS - 1);
                if (am) {
                    F3 x0 = ldl(C, c-1), x1 = ldl(C, c), x2 = ldl(C, c+1);
                    F3 d0 = nrmv(subv(x0, x1)), d1 = nrmv(subv(x2, x1));
                    float cv = dotv(d0, d1);
                    float t = 1.f - cv*cv + EPSF;
                    sa = t * rsqrtf(t);
                    ca = cv;
                }
                feat[rl*NODE_IN + 12 + 2*c] = sa; feat[rl*NODE_IN + 12 + 2*c + 1] = ca;
            } else {
                int a = role - 6;
                int atom = (a == 0) ? 0 : (a + 1);   // keep atoms {0,2,3,4,5}
                F3 x  = ldl(C, atom);
                F3 cx = ld3(central, (long)r);
                F3 d  = subv(x, cx);
                float d2 = dotv(d, d);
                feat[rl*NODE_IN + 24 + a] = 0.5f * __logf(d2 + EPSF);
                float inv = rsqrtf(fmaxf(d2, 1e-24f));
                float nx = d.x*inv, ny = d.y*inv, nz = d.z*inv;
                const float* Q = Qbuf + (size_t)r * 9;
                #pragma unroll
                for (int i = 0; i < 3; i++)
                    feat[rl*NODE_IN + 29 + a*3 + i] = Q[0+i]*nx + Q[3+i]*ny + Q[6+i]*nz;
            }
        }
        __syncthreads();

        int ch = tid & 127;
        int sg = tid >> 7;          // residue sub-group 0/1
        int w  = tid >> 6;          // wave 0..3
        for (int it = 0; it < 8; ++it) {
            int rl = it * 2 + sg;
            float acc = bS[ch];
            #pragma unroll
            for (int i = 0; i < NODE_IN; i++)
                acc += feat[rl*NODE_IN + i] * Wlds[i * HID + ch];
            float s = acc;
            #pragma unroll
            for (int m = 1; m < 64; m <<= 1) s += __shfl_xor(s, m, 64);
            if ((tid & 63) == 0) red[w] = s;
            __syncthreads();
            float mu = (red[2*sg] + red[2*sg+1]) * (1.f / HID);
            float dv = acc - mu;
            float q = dv * dv;
            #pragma unroll
            for (int m = 1; m < 64; m <<= 1) q += __shfl_xor(q, m, 64);
            if ((tid & 63) == 0) red[4 + w] = q;
            __syncthreads();
            float var = (red[4 + 2*sg] + red[4 + 2*sg + 1]) * (1.f / HID);
            outV[(size_t)(r0 + rl) * HID + ch] = dv * rsqrtf(var + LN_EPS) * lwS[ch] + lbS[ch];
        }
    }
}

extern "C" void kernel_launch(void* const* d_in, const int* in_sizes, int n_in,
                              void* d_out, int out_size, void* d_ws, size_t ws_size,
                              hipStream_t stream) {
    (void)in_sizes; (void)n_in; (void)out_size; (void)ws_size;
    const float* coords  = (const float*)d_in[0];
    const float* central = (const float*)d_in[1];
    const float* node_W  = (const float*)d_in[2];
    const float* node_b  = (const float*)d_in[3];
    const float* node_lw = (const float*)d_in[4];
    const float* node_lb = (const float*)d_in[5];
    const float* edge_W  = (const float*)d_in[6];
    const float* edge_b  = (const float*)d_in[7];
    const float* edge_lw = (const float*)d_in[8];
    const float* edge_lb = (const float*)d_in[9];
    const int*   batch   = (const int*)d_in[10];
    const int*   eidx    = (const int*)d_in[11];

    // ws: [Wpack bf16: 88064 el = 176128 B][Qbuf: 270000 f][qval: 30000 i] ~= 1.38 MB
    unsigned short* Wpack = (unsigned short*)d_ws;
    float* Qbuf = (float*)((char*)d_ws + (size_t)EDGE_IN * HID * 2);
    int*   qval = (int*)(Qbuf + (size_t)N_RES * 9);

    float* outV = (float*)d_out;
    float* outE = outV + (size_t)N_RES * HID;

    hipLaunchKernelGGL(k_prep, dim3(KSTEPS + (N_RES + 255) / 256), dim3(256), 0, stream,
                       edge_W, central, batch, Wpack, Qbuf, qval);
    hipLaunchKernelGGL(k_main, dim3(NEBLK + NNBLK), dim3(256), 0, stream,
                       coords, central, node_W, node_b, node_lw, node_lb, batch, eidx,
                       Wpack, edge_b, edge_lw, edge_lb, Qbuf, qval, outV, outE);
}